// Round 9
// baseline (285.359 us; speedup 1.0000x reference)
//
#include <hip/hip_runtime.h>
#include <hip/hip_cooperative_groups.h>

// LinearAttention: B=2, L=2048, D=1024, H=16, d=64.
// R14: cvt_all ; gemm_bt8 (R1-proven) ; mid_fused (kv_local + kv_prefix +
// attn_chunk in ONE cooperative kernel, two grid.sync()) ; gemm_out64.
// R13 post-mortem: in-GEMM f32 staging regressed (+21us on QKV; FETCH 2x,
// reg-staging beat by glds per m151) -- reverted to R11 kernels everywhere.
// R14's single change: the three middle kernels share grid (16,32)x256, so
// they fuse VERBATIM (same code, same mloc/states global round-trips, same
// numerics) with grid syncs replacing two dispatch boundaries. Co-residency:
// 512 blocks = 2/CU, LDS 64KB/block (union of kv 34KB / attn 64KB regions),
// __launch_bounds__(256,2).

#define DEV __device__ __forceinline__

namespace cg = cooperative_groups;

typedef __attribute__((ext_vector_type(8))) short bf16x8;
typedef __attribute__((ext_vector_type(4))) float f32x4;

DEV ushort f2bf(float f) {
  union { float f; unsigned u; } v; v.f = f;
  unsigned r = v.u + 0x7fffu + ((v.u >> 16) & 1u);
  return (ushort)(r >> 16);
}
DEV void glds16(const ushort* g, ushort* l) {
  __builtin_amdgcn_global_load_lds(
      (const __attribute__((address_space(1))) unsigned int*)g,
      (__attribute__((address_space(3))) unsigned int*)l, 16, 0, 0);
}

__global__ __launch_bounds__(256) void cvt_all(const float* __restrict__ x,
                                               const float* __restrict__ Ww,
                                               const float* __restrict__ Ow,
                                               ushort* __restrict__ xb,
                                               ushort* __restrict__ wqkvb,
                                               ushort* __restrict__ outwb) {
  int i = blockIdx.x * 256 + threadIdx.x;
  const float* src; ushort* dst; int off;
  if (i < 1048576)      { src = x;  dst = xb;    off = i; }
  else if (i < 1835008) { src = Ww; dst = wqkvb; off = i - 1048576; }
  else                  { src = Ow; dst = outwb; off = i - 1835008; }
  float4 v = ((const float4*)src)[off];
  ushort4 o;
  o.x = f2bf(v.x); o.y = f2bf(v.y); o.z = f2bf(v.z); o.w = f2bf(v.w);
  ((ushort4*)dst)[off] = o;
}

// ---------------------------------------------------------------------------
// QKV GEMM (R1-proven): 256x256 tiles, BK=64 dbuf, 8 waves (2M x 4N),
// 4 phases/tile with raw barriers, vmcnt(0) twice per 8 phases, T2 swizzle
// (pre-swizzled global source + XOR ds_read), T1 XCD swizzle, T5 setprio.
// ---------------------------------------------------------------------------
template <bool OUT_BF16, bool KSCALE>
__global__ __launch_bounds__(512, 2) void gemm_bt8(const ushort* __restrict__ A,
                                                   const ushort* __restrict__ Bw,
                                                   const float* __restrict__ bias,
                                                   void* __restrict__ Cout,
                                                   int M, int N, int K) {
  __shared__ __align__(16) ushort As[2][16384];
  __shared__ __align__(16) ushort Bs[2][16384];
  const int t = threadIdx.x;
  const int lane = t & 63, wid = t >> 6;
  const int quad = lane >> 4, l16 = lane & 15;
  const int wm2 = wid >> 2, wn4 = wid & 3;

  const int nwg = gridDim.x;
  const int bid = blockIdx.x;
  const int wg = (bid & 7) * (nwg >> 3) + (bid >> 3);
  const int nbx = N >> 8;
  const int bx = wg % nbx, by = wg / nbx;
  const int bm = by << 8, bn = bx << 8;

  const int srow = t >> 3;
  const int scol = ((t & 7) ^ (srow & 7)) << 3;
  const ushort* ag = A + (size_t)(bm + srow) * K + scol;
  const ushort* bg = Bw + (size_t)(bn + srow) * K + scol;
  const int NT = K >> 6;

  f32x4 acc[8][4];
  const f32x4 z = {0.f, 0.f, 0.f, 0.f};
#pragma unroll
  for (int i = 0; i < 8; ++i)
#pragma unroll
    for (int j = 0; j < 4; ++j) acc[i][j] = z;

  const int aRow = wm2 * 128 + l16;
  const int bRow = wn4 * 64 + l16;
  const int cxor = l16 & 7;

#define SG_A(bufi, kt, h, j) \
  glds16(ag + (size_t)((h)*128 + (j)*64) * K + ((kt) << 6), \
         &As[bufi][(h)*8192 + (j)*4096 + wid * 512])
#define SG_B(bufi, kt, h, j) \
  glds16(bg + (size_t)((h)*128 + (j)*64) * K + ((kt) << 6), \
         &Bs[bufi][(h)*8192 + (j)*4096 + wid * 512])
#define RD_A(bufi, mi, kc) \
  (*(const bf16x8*)&As[bufi][(aRow + (mi)*16) * 64 + ((((kc)*4 + quad) ^ cxor) << 3)])
#define RD_B(bufi, nj, kc) \
  (*(const bf16x8*)&Bs[bufi][(bRow + (nj)*16) * 64 + ((((kc)*4 + quad) ^ cxor) << 3)])

  SG_A(0, 0, 0, 0); SG_A(0, 0, 0, 1); SG_A(0, 0, 1, 0); SG_A(0, 0, 1, 1);
  SG_B(0, 0, 0, 0); SG_B(0, 0, 0, 1); SG_B(0, 0, 1, 0); SG_B(0, 0, 1, 1);
  asm volatile("s_waitcnt vmcnt(0)" ::: "memory");
  __builtin_amdgcn_s_barrier();

  bf16x8 bf[4][2], af[2][2];

#define LOAD_AF(rb, mi0) \
  af[0][0] = RD_A(rb, (mi0), 0); af[0][1] = RD_A(rb, (mi0), 1); \
  af[1][0] = RD_A(rb, (mi0) + 1, 0); af[1][1] = RD_A(rb, (mi0) + 1, 1);

#define MFMA16(mi0) \
  __builtin_amdgcn_s_setprio(1); \
  _Pragma("unroll") \
  for (int nj = 0; nj < 4; ++nj) { \
    acc[(mi0)][nj] = __builtin_amdgcn_mfma_f32_16x16x32_bf16(af[0][0], bf[nj][0], acc[(mi0)][nj], 0, 0, 0); \
    acc[(mi0)][nj] = __builtin_amdgcn_mfma_f32_16x16x32_bf16(af[0][1], bf[nj][1], acc[(mi0)][nj], 0, 0, 0); \
    acc[(mi0) + 1][nj] = __builtin_amdgcn_mfma_f32_16x16x32_bf16(af[1][0], bf[nj][0], acc[(mi0) + 1][nj], 0, 0, 0); \
    acc[(mi0) + 1][nj] = __builtin_amdgcn_mfma_f32_16x16x32_bf16(af[1][1], bf[nj][1], acc[(mi0) + 1][nj], 0, 0, 0); \
  } \
  __builtin_amdgcn_s_setprio(0);

#define HALFSTEP(rb, sb, stTile, doSt) do { \
    if (doSt) { SG_A(sb, stTile, 0, 0); SG_A(sb, stTile, 0, 1); \
                SG_A(sb, stTile, 1, 0); SG_A(sb, stTile, 1, 1); } \
    _Pragma("unroll") \
    for (int nj = 0; nj < 4; ++nj) { bf[nj][0] = RD_B(rb, nj, 0); bf[nj][1] = RD_B(rb, nj, 1); } \
    LOAD_AF(rb, 0); \
    __builtin_amdgcn_s_barrier(); \
    MFMA16(0); \
    __builtin_amdgcn_s_barrier(); \
    if (doSt) { SG_B(sb, stTile, 0, 0); SG_B(sb, stTile, 0, 1); } \
    LOAD_AF(rb, 2); \
    __builtin_amdgcn_s_barrier(); \
    MFMA16(2); \
    __builtin_amdgcn_s_barrier(); \
    if (doSt) { SG_B(sb, stTile, 1, 0); SG_B(sb, stTile, 1, 1); } \
    LOAD_AF(rb, 4); \
    __builtin_amdgcn_s_barrier(); \
    MFMA16(4); \
    __builtin_amdgcn_s_barrier(); \
    LOAD_AF(rb, 6); \
    __builtin_amdgcn_s_barrier(); \
    MFMA16(6); \
    asm volatile("s_waitcnt vmcnt(0)" ::: "memory"); \
    __builtin_amdgcn_s_barrier(); \
  } while (0)

  const int half = NT >> 1;
  for (int i = 0; i < half; ++i) {
    HALFSTEP(0, 1, 2 * i + 1, true);
    HALFSTEP(1, 0, 2 * i + 2, (i < half - 1));
  }

#undef HALFSTEP
#undef MFMA16
#undef LOAD_AF
#undef RD_A
#undef RD_B
#undef SG_A
#undef SG_B

#pragma unroll
  for (int mi = 0; mi < 8; ++mi)
#pragma unroll
    for (int nj = 0; nj < 4; ++nj) {
      const int col = bn + wn4 * 64 + nj * 16 + l16;
      const float bv = bias[col];
      float sc = 1.f;
      if (KSCALE) sc = ((col >> 10) == 1) ? 0.125f : 1.f;
#pragma unroll
      for (int r = 0; r < 4; ++r) {
        const int row = bm + wm2 * 128 + mi * 16 + quad * 4 + r;
        const float v = (acc[mi][nj][r] + bv) * sc;
        if (OUT_BF16)
          ((ushort*)Cout)[(size_t)row * N + col] = f2bf(v);
        else
          ((float*)Cout)[(size_t)row * N + col] = v;
      }
    }
}

// Out projection: BM=64, BN=128, BK=32 -> 512 blocks (2/CU), identity staging.
__global__ __launch_bounds__(256) void gemm_out64(const ushort* __restrict__ A,
                                                  const ushort* __restrict__ Bw,
                                                  const float* __restrict__ bias,
                                                  float* __restrict__ C,
                                                  int M, int N, int K) {
  __shared__ ushort As[64 * 32];
  __shared__ ushort Bs[128 * 32];
  const int t = threadIdx.x;
  const int wid = t >> 6, lane = t & 63;
  const int quad = lane >> 4, l16 = lane & 15;
  const int bm = blockIdx.y * 64, bn = blockIdx.x * 128;
  const int wn = wid * 32;

  f32x4 acc[4][2];
  const f32x4 z = {0.f, 0.f, 0.f, 0.f};
#pragma unroll
  for (int i = 0; i < 4; ++i) { acc[i][0] = z; acc[i][1] = z; }

  const ushort* ag = A + (size_t)(bm + (t >> 2)) * K + ((t & 3) * 8);
  const ushort* bg = Bw + (size_t)(bn + (t >> 2)) * K + ((t & 3) * 8);
  ushort* asl = As + wid * 512;
  ushort* bsl = Bs + wid * 512;
  const size_t rowskip = (size_t)64 * K;

  for (int k0 = 0; k0 < K; k0 += 32) {
    glds16(ag + k0, asl);
    glds16(bg + k0, bsl);
    glds16(bg + k0 + rowskip, bsl + 2048);
    __syncthreads();
    bf16x8 af[4], bf[2];
#pragma unroll
    for (int i = 0; i < 4; ++i)
      af[i] = *(const bf16x8*)(As + (i * 16 + l16) * 32 + quad * 8);
#pragma unroll
    for (int j = 0; j < 2; ++j)
      bf[j] = *(const bf16x8*)(Bs + (wn + j * 16 + l16) * 32 + quad * 8);
#pragma unroll
    for (int i = 0; i < 4; ++i)
#pragma unroll
      for (int j = 0; j < 2; ++j)
        acc[i][j] = __builtin_amdgcn_mfma_f32_16x16x32_bf16(af[i], bf[j], acc[i][j], 0, 0, 0);
    __syncthreads();
  }

#pragma unroll
  for (int i = 0; i < 4; ++i)
#pragma unroll
    for (int j = 0; j < 2; ++j) {
      const int col = bn + wn + j * 16 + l16;
      const float bv = bias[col];
#pragma unroll
      for (int r = 0; r < 4; ++r) {
        const int row = bm + i * 16 + quad * 4 + r;
        C[(size_t)row * N + col] = acc[i][j][r] + bv;
      }
    }
}

// ---------------------------------------------------------------------------
// Cooperative fusion of kv_local + kv_prefix + attn_chunk (grid (16,32)x256,
// 512 blocks = 2/CU co-resident). Stage bodies are VERBATIM the R11 kernels;
// grid.sync() (device-scope fence + barrier) replaces the two dispatch
// boundaries that ordered mloc->prefix->states across XCDs.
// LDS: one 64 KB region, union of kv's kT/vT (34 KB) and attn's P/U (64 KB).
// ---------------------------------------------------------------------------
__global__ __launch_bounds__(256, 2) void mid_fused(const ushort* __restrict__ qkv,
                                                    float* __restrict__ mlocT,
                                                    ushort* __restrict__ statesT,
                                                    ushort* __restrict__ yb) {
  cg::grid_group grid = cg::this_grid();
  const int c = blockIdx.x, bh = blockIdx.y;
  const int b = bh >> 4, hd = bh & 15;
  const int t = threadIdx.x;
  const int wid = t >> 6, lane = t & 63;
  const int quad = lane >> 4, l16 = lane & 15;

  __shared__ __align__(16) ushort SH[32768];  // 64 KB

  // ---------------- stage 1: kv_local (c, bh) ----------------
  {
    ushort* kT = SH;         // [f:64][s:128] stride 136
    ushort* vT = SH + 8704;  // [e:64][s:128] stride 136
    {
      const int x = t & 127;
      const int isv = t >> 7;
      const int rp = x >> 1;
      const int half = (x & 1) * 32;
      const ushort* g0 = qkv + (size_t)(b * 2048 + c * 128 + 2 * rp) * 3072 +
                         1024 + isv * 1024 + hd * 64 + half;
      const ushort* g1 = g0 + 3072;
      ushort ta[32], tb[32];
#pragma unroll
      for (int q = 0; q < 4; ++q) {
        *(uint4*)(ta + q * 8) = *(const uint4*)(g0 + q * 8);
        *(uint4*)(tb + q * 8) = *(const uint4*)(g1 + q * 8);
      }
      ushort* dst = isv ? vT : kT;
#pragma unroll
      for (int j = 0; j < 32; ++j) {
        unsigned pk = (unsigned)ta[j] | ((unsigned)tb[j] << 16);
        *(unsigned*)(dst + (half + j) * 136 + 2 * rp) = pk;
      }
    }
    __syncthreads();

    const f32x4 z = {0.f, 0.f, 0.f, 0.f};
    f32x4 acc[4];
#pragma unroll
    for (int ct = 0; ct < 4; ++ct) acc[ct] = z;
#pragma unroll
    for (int kc = 0; kc < 4; ++kc) {
      bf16x8 afr = *(const bf16x8*)(vT + (wid * 16 + l16) * 136 + kc * 32 + quad * 8);
#pragma unroll
      for (int ct = 0; ct < 4; ++ct) {
        bf16x8 bfr = *(const bf16x8*)(kT + (ct * 16 + l16) * 136 + kc * 32 + quad * 8);
        acc[ct] = __builtin_amdgcn_mfma_f32_16x16x32_bf16(afr, bfr, acc[ct], 0, 0, 0);
      }
    }
    float* outp = mlocT + ((size_t)bh * 16 + c) * 4096;
#pragma unroll
    for (int ct = 0; ct < 4; ++ct)
#pragma unroll
      for (int r = 0; r < 4; ++r)
        outp[(wid * 16 + quad * 4 + r) * 64 + ct * 16 + l16] = acc[ct][r];
  }

  grid.sync();

  // ---------------- stage 2: kv_prefix (slice=c, bh) ----------------
  {
    const int eidx = c * 256 + t;
    float run = 0.f;
    for (int cc = 0; cc < 16; ++cc) {
      const size_t idx = ((size_t)bh * 16 + cc) * 4096 + eidx;
      statesT[idx] = f2bf(run);
      run += mlocT[idx];
    }
  }

  grid.sync();

  // ---------------- stage 3: attn_chunk (c, bh) ----------------
  {
    const int l0 = c * 128;
    ushort* P = SH;           // 16384 ushorts
    ushort* U = SH + 16384;   // 16384 ushorts
    ushort* Qs = U;
    ushort* Ks = U + 8192;
    ushort* vT = U;           // phase2: [e:64][s:128] stride 136
    ushort* sT = U + 8704;    // phase2: [e:64][f:64]  stride 72

    {  // zero P
      uint4 zz; zz.x = zz.y = zz.z = zz.w = 0u;
      uint4* p4 = (uint4*)P;
#pragma unroll
      for (int i = 0; i < 8; ++i) p4[i * 256 + t] = zz;
    }
    {  // stage Q,K swizzled
      const int kcs = ((lane & 7) ^ (lane >> 3)) * 8;
      const ushort* qg = qkv + (size_t)(b * 2048 + l0 + (t >> 3)) * 3072 + hd * 64 + kcs;
      ushort* ql = Qs + wid * 512;
      ushort* kl = Ks + wid * 512;
#pragma unroll
      for (int h2 = 0; h2 < 4; ++h2) {
        glds16(qg + (size_t)h2 * 32 * 3072, ql + h2 * 2048);
        glds16(qg + (size_t)h2 * 32 * 3072 + 1024, kl + h2 * 2048);
      }
    }
    __syncthreads();

    bf16x8 qf[2][2];
#pragma unroll
    for (int i = 0; i < 2; ++i) {
      const int rt = i ? (7 - wid) : wid;
#pragma unroll
      for (int kc = 0; kc < 2; ++kc)
        qf[i][kc] = *(const bf16x8*)(Qs + (rt * 16 + l16) * 64 +
                                     (((kc * 4 + quad) ^ (l16 & 7)) * 8));
    }

    const f32x4 z4 = {0.f, 0.f, 0.f, 0.f};
    f32x4 pacc[2][8];
#pragma unroll
    for (int i = 0; i < 2; ++i)
#pragma unroll
      for (int j = 0; j < 8; ++j) pacc[i][j] = z4;

#pragma unroll
    for (int i = 0; i < 2; ++i) {
      const int rt = i ? (7 - wid) : wid;
#pragma unroll
      for (int tj = 0; tj < 8; ++tj) {
        if (tj <= rt) {
#pragma unroll
          for (int kc = 0; kc < 2; ++kc) {
            bf16x8 kfr = *(const bf16x8*)(Ks + (tj * 16 + l16) * 64 +
                                          (((kc * 4 + quad) ^ (l16 & 7)) * 8));
            pacc[i][tj] = __builtin_amdgcn_mfma_f32_16x16x32_bf16(qf[i][kc], kfr, pacc[i][tj], 0, 0, 0);
          }
        }
      }
    }
    __syncthreads();

#pragma unroll
    for (int i = 0; i < 2; ++i) {
      const int rt = i ? (7 - wid) : wid;
#pragma unroll
      for (int tj = 0; tj < 8; ++tj) {
        if (tj <= rt) {
#pragma unroll
          for (int r = 0; r < 4; ++r) {
            const int row = rt * 16 + quad * 4 + r;
            const int scol = tj * 16 + l16;
            const float v = (scol <= row) ? pacc[i][tj][r] : 0.f;
            P[row * 128 + (((scol >> 3) ^ (row & 7)) * 8) + (scol & 7)] = f2bf(v);
          }
        }
      }
    }
    {  // stage V transposed: vT[e][s] stride 136, s-pair-packed b32 writes
      const int p = t >> 2;
      const int eq = (t & 3) * 16;
      const ushort* vg0 = qkv + (size_t)(b * 2048 + l0 + 2 * p) * 3072 + 2048 + hd * 64 + eq;
      const ushort* vg1 = vg0 + 3072;
      ushort ta[16], tb[16];
      *(uint4*)(ta + 0) = *(const uint4*)(vg0 + 0);
      *(uint4*)(ta + 8) = *(const uint4*)(vg0 + 8);
      *(uint4*)(tb + 0) = *(const uint4*)(vg1 + 0);
      *(uint4*)(tb + 8) = *(const uint4*)(vg1 + 8);
#pragma unroll
      for (int j = 0; j < 16; ++j) {
        unsigned pk = (unsigned)ta[j] | ((unsigned)tb[j] << 16);
        *(unsigned*)(vT + (eq + j) * 136 + 2 * p) = pk;
      }
    }
    {  // stage state: 2 coalesced uint4 per thread -> sT stride 72
      const ushort* sg = statesT + ((size_t)bh * 16 + c) * 4096;
#pragma unroll
      for (int h = 0; h < 2; ++h) {
        const int cc2 = h * 256 + t;
        uint4 d = *(const uint4*)(sg + cc2 * 8);
        *(uint4*)(sT + (cc2 >> 3) * 72 + (cc2 & 7) * 8) = d;
      }
    }
    __syncthreads();

    f32x4 yacc[2][4];
#pragma unroll
    for (int i = 0; i < 2; ++i)
#pragma unroll
      for (int j = 0; j < 4; ++j) yacc[i][j] = z4;

#pragma unroll
    for (int i = 0; i < 2; ++i) {
      const int rt = i ? (7 - wid) : wid;
      const int kcmax = rt >> 1;
#pragma unroll
      for (int kc = 0; kc < 4; ++kc) {
        if (kc <= kcmax) {
          const int prow = rt * 16 + l16;
          bf16x8 pf;
          *(uint4*)&pf = *(const uint4*)(P + prow * 128 + (((kc * 4 + quad) ^ (prow & 7)) * 8));
#pragma unroll
          for (int ct = 0; ct < 4; ++ct) {
            bf16x8 vf = *(const bf16x8*)(vT + (ct * 16 + l16) * 136 + kc * 32 + quad * 8);
            yacc[i][ct] = __builtin_amdgcn_mfma_f32_16x16x32_bf16(pf, vf, yacc[i][ct], 0, 0, 0);
          }
        }
      }
#pragma unroll
      for (int kc = 0; kc < 2; ++kc) {
#pragma unroll
        for (int ct = 0; ct < 4; ++ct) {
          bf16x8 sf = *(const bf16x8*)(sT + (ct * 16 + l16) * 72 + kc * 32 + quad * 8);
          yacc[i][ct] = __builtin_amdgcn_mfma_f32_16x16x32_bf16(qf[i][kc], sf, yacc[i][ct], 0, 0, 0);
        }
      }
    }

#pragma unroll
    for (int i = 0; i < 2; ++i) {
      const int rt = i ? (7 - wid) : wid;
#pragma unroll
      for (int ct = 0; ct < 4; ++ct) {
#pragma unroll
        for (int r = 0; r < 4; ++r) {
          const int row = rt * 16 + quad * 4 + r;
          const int e = ct * 16 + l16;
          yb[(size_t)(b * 2048 + l0 + row) * 1024 + hd * 64 + e] = f2bf(yacc[i][ct][r]);
        }
      }
    }
  }
}

extern "C" void kernel_launch(void* const* d_in, const int* in_sizes, int n_in,
                              void* d_out, int out_size, void* d_ws, size_t ws_size,
                              hipStream_t stream) {
  const float* x  = (const float*)d_in[0];
  const float* Ww = (const float*)d_in[1];
  const float* Wb = (const float*)d_in[2];
  const float* Ow = (const float*)d_in[3];
  const float* Ob = (const float*)d_in[4];
  float* out = (float*)d_out;

  char* ws = (char*)d_ws;
  ushort* xb      = (ushort*)(ws);
  ushort* wqkvb   = (ushort*)(ws + (size_t)8  * 1024 * 1024);
  ushort* outwb   = (ushort*)(ws + (size_t)14 * 1024 * 1024);
  ushort* qkvb    = (ushort*)(ws + (size_t)16 * 1024 * 1024);
  float*  mlocT   = (float*) (ws + (size_t)40 * 1024 * 1024);
  ushort* statesT = (ushort*)(ws + (size_t)48 * 1024 * 1024);
  ushort* yb      = (ushort*)(ws + (size_t)52 * 1024 * 1024);

  cvt_all<<<8192, 256, 0, stream>>>(x, Ww, Ow, xb, wqkvb, outwb);
  // 256^2 tiles: grid = (3072/256)*(4096/256) = 192 blocks (1D, XCD-swizzled).
  gemm_bt8<true, true><<<dim3(192), 512, 0, stream>>>(xb, wqkvb, Wb, (void*)qkvb, 4096, 3072, 1024);
  {
    void* args[] = {(void*)&qkvb, (void*)&mlocT, (void*)&statesT, (void*)&yb};
    hipLaunchCooperativeKernel((const void*)mid_fused, dim3(16, 32), dim3(256),
                               args, 0, stream);
  }
  gemm_out64<<<dim3(8, 64), 256, 0, stream>>>(yb, outwb, Ob, out, 4096, 1024, 1024);
}

// Round 10
// 166.030 us; speedup vs baseline: 1.7187x; 1.7187x over previous
//
#include <hip/hip_runtime.h>

// LinearAttention: B=2, L=2048, D=1024, H=16, d=64.
// R15 = measured-best recombination:
//   cvt_all2 (x+Wqkv only, 7168 blocks) ; gemm_bt8 (R1-proven) ; kv_local
//   (R10 packed) ; kv_prefix ; attn_chunk (R10/R11) ; gemm_out64f (R13's
//   inline f32->bf16 B staging -- its non-QKV remainder measured 5us BETTER
//   than the cvt_all path: smaller cvt + no outwb round-trip, and out64's
//   staging VALU is idle so inline cvt is free there).
// R14 post-mortem: cooperative grid.sync() fusion = 120us kernel (sync cost
// >> launch gaps) -- cooperative path dead. R13 post-mortem: inline cvt in
// the QKV GEMM loses (m151: reg-staging < glds on the critical path) but its
// out64f + smaller-cvt pieces WON; this round keeps exactly those.

#define DEV __device__ __forceinline__

typedef __attribute__((ext_vector_type(8))) short bf16x8;
typedef __attribute__((ext_vector_type(4))) float f32x4;

DEV ushort f2bf(float f) {
  union { float f; unsigned u; } v; v.f = f;
  unsigned r = v.u + 0x7fffu + ((v.u >> 16) & 1u);
  return (ushort)(r >> 16);
}
DEV void glds16(const ushort* g, ushort* l) {
  __builtin_amdgcn_global_load_lds(
      (const __attribute__((address_space(1))) unsigned int*)g,
      (__attribute__((address_space(3))) unsigned int*)l, 16, 0, 0);
}
// 8 f32 -> 8 bf16 (RNE) packed into a uint4, via v_cvt_pk_bf16_f32.
DEV uint4 pk8(float4 a, float4 b) {
  uint4 o;
  asm("v_cvt_pk_bf16_f32 %0, %1, %2" : "=v"(o.x) : "v"(a.x), "v"(a.y));
  asm("v_cvt_pk_bf16_f32 %0, %1, %2" : "=v"(o.y) : "v"(a.z), "v"(a.w));
  asm("v_cvt_pk_bf16_f32 %0, %1, %2" : "=v"(o.z) : "v"(b.x), "v"(b.y));
  asm("v_cvt_pk_bf16_f32 %0, %1, %2" : "=v"(o.w) : "v"(b.z), "v"(b.w));
  return o;
}

// Convert x (1048576 float4) + Wqkv (786432 float4) only: 7168 blocks.
__global__ __launch_bounds__(256) void cvt_all2(const float* __restrict__ x,
                                                const float* __restrict__ Ww,
                                                ushort* __restrict__ xb,
                                                ushort* __restrict__ wqkvb) {
  int i = blockIdx.x * 256 + threadIdx.x;
  const float* src; ushort* dst; int off;
  if (i < 1048576) { src = x;  dst = xb;    off = i; }
  else             { src = Ww; dst = wqkvb; off = i - 1048576; }
  float4 v = ((const float4*)src)[off];
  ushort4 o;
  o.x = f2bf(v.x); o.y = f2bf(v.y); o.z = f2bf(v.z); o.w = f2bf(v.w);
  ((ushort4*)dst)[off] = o;
}

// ---------------------------------------------------------------------------
// QKV GEMM (R1-proven): 256x256 tiles, BK=64 dbuf, 8 waves (2M x 4N),
// 4 phases/tile with raw barriers, vmcnt(0) twice per 8 phases, T2 swizzle
// (pre-swizzled global source + XOR ds_read), T1 XCD swizzle, T5 setprio.
// ---------------------------------------------------------------------------
template <bool OUT_BF16, bool KSCALE>
__global__ __launch_bounds__(512, 2) void gemm_bt8(const ushort* __restrict__ A,
                                                   const ushort* __restrict__ Bw,
                                                   const float* __restrict__ bias,
                                                   void* __restrict__ Cout,
                                                   int M, int N, int K) {
  __shared__ __align__(16) ushort As[2][16384];
  __shared__ __align__(16) ushort Bs[2][16384];
  const int t = threadIdx.x;
  const int lane = t & 63, wid = t >> 6;
  const int quad = lane >> 4, l16 = lane & 15;
  const int wm2 = wid >> 2, wn4 = wid & 3;

  const int nwg = gridDim.x;
  const int bid = blockIdx.x;
  const int wg = (bid & 7) * (nwg >> 3) + (bid >> 3);
  const int nbx = N >> 8;
  const int bx = wg % nbx, by = wg / nbx;
  const int bm = by << 8, bn = bx << 8;

  const int srow = t >> 3;
  const int scol = ((t & 7) ^ (srow & 7)) << 3;
  const ushort* ag = A + (size_t)(bm + srow) * K + scol;
  const ushort* bg = Bw + (size_t)(bn + srow) * K + scol;
  const int NT = K >> 6;

  f32x4 acc[8][4];
  const f32x4 z = {0.f, 0.f, 0.f, 0.f};
#pragma unroll
  for (int i = 0; i < 8; ++i)
#pragma unroll
    for (int j = 0; j < 4; ++j) acc[i][j] = z;

  const int aRow = wm2 * 128 + l16;
  const int bRow = wn4 * 64 + l16;
  const int cxor = l16 & 7;

#define SG_A(bufi, kt, h, j) \
  glds16(ag + (size_t)((h)*128 + (j)*64) * K + ((kt) << 6), \
         &As[bufi][(h)*8192 + (j)*4096 + wid * 512])
#define SG_B(bufi, kt, h, j) \
  glds16(bg + (size_t)((h)*128 + (j)*64) * K + ((kt) << 6), \
         &Bs[bufi][(h)*8192 + (j)*4096 + wid * 512])
#define RD_A(bufi, mi, kc) \
  (*(const bf16x8*)&As[bufi][(aRow + (mi)*16) * 64 + ((((kc)*4 + quad) ^ cxor) << 3)])
#define RD_B(bufi, nj, kc) \
  (*(const bf16x8*)&Bs[bufi][(bRow + (nj)*16) * 64 + ((((kc)*4 + quad) ^ cxor) << 3)])

  SG_A(0, 0, 0, 0); SG_A(0, 0, 0, 1); SG_A(0, 0, 1, 0); SG_A(0, 0, 1, 1);
  SG_B(0, 0, 0, 0); SG_B(0, 0, 0, 1); SG_B(0, 0, 1, 0); SG_B(0, 0, 1, 1);
  asm volatile("s_waitcnt vmcnt(0)" ::: "memory");
  __builtin_amdgcn_s_barrier();

  bf16x8 bf[4][2], af[2][2];

#define LOAD_AF(rb, mi0) \
  af[0][0] = RD_A(rb, (mi0), 0); af[0][1] = RD_A(rb, (mi0), 1); \
  af[1][0] = RD_A(rb, (mi0) + 1, 0); af[1][1] = RD_A(rb, (mi0) + 1, 1);

#define MFMA16(mi0) \
  __builtin_amdgcn_s_setprio(1); \
  _Pragma("unroll") \
  for (int nj = 0; nj < 4; ++nj) { \
    acc[(mi0)][nj] = __builtin_amdgcn_mfma_f32_16x16x32_bf16(af[0][0], bf[nj][0], acc[(mi0)][nj], 0, 0, 0); \
    acc[(mi0)][nj] = __builtin_amdgcn_mfma_f32_16x16x32_bf16(af[0][1], bf[nj][1], acc[(mi0)][nj], 0, 0, 0); \
    acc[(mi0) + 1][nj] = __builtin_amdgcn_mfma_f32_16x16x32_bf16(af[1][0], bf[nj][0], acc[(mi0) + 1][nj], 0, 0, 0); \
    acc[(mi0) + 1][nj] = __builtin_amdgcn_mfma_f32_16x16x32_bf16(af[1][1], bf[nj][1], acc[(mi0) + 1][nj], 0, 0, 0); \
  } \
  __builtin_amdgcn_s_setprio(0);

#define HALFSTEP(rb, sb, stTile, doSt) do { \
    if (doSt) { SG_A(sb, stTile, 0, 0); SG_A(sb, stTile, 0, 1); \
                SG_A(sb, stTile, 1, 0); SG_A(sb, stTile, 1, 1); } \
    _Pragma("unroll") \
    for (int nj = 0; nj < 4; ++nj) { bf[nj][0] = RD_B(rb, nj, 0); bf[nj][1] = RD_B(rb, nj, 1); } \
    LOAD_AF(rb, 0); \
    __builtin_amdgcn_s_barrier(); \
    MFMA16(0); \
    __builtin_amdgcn_s_barrier(); \
    if (doSt) { SG_B(sb, stTile, 0, 0); SG_B(sb, stTile, 0, 1); } \
    LOAD_AF(rb, 2); \
    __builtin_amdgcn_s_barrier(); \
    MFMA16(2); \
    __builtin_amdgcn_s_barrier(); \
    if (doSt) { SG_B(sb, stTile, 1, 0); SG_B(sb, stTile, 1, 1); } \
    LOAD_AF(rb, 4); \
    __builtin_amdgcn_s_barrier(); \
    MFMA16(4); \
    __builtin_amdgcn_s_barrier(); \
    LOAD_AF(rb, 6); \
    __builtin_amdgcn_s_barrier(); \
    MFMA16(6); \
    asm volatile("s_waitcnt vmcnt(0)" ::: "memory"); \
    __builtin_amdgcn_s_barrier(); \
  } while (0)

  const int half = NT >> 1;
  for (int i = 0; i < half; ++i) {
    HALFSTEP(0, 1, 2 * i + 1, true);
    HALFSTEP(1, 0, 2 * i + 2, (i < half - 1));
  }

#undef HALFSTEP
#undef MFMA16
#undef LOAD_AF
#undef RD_A
#undef RD_B
#undef SG_A
#undef SG_B

#pragma unroll
  for (int mi = 0; mi < 8; ++mi)
#pragma unroll
    for (int nj = 0; nj < 4; ++nj) {
      const int col = bn + wn4 * 64 + nj * 16 + l16;
      const float bv = bias[col];
      float sc = 1.f;
      if (KSCALE) sc = ((col >> 10) == 1) ? 0.125f : 1.f;
#pragma unroll
      for (int r = 0; r < 4; ++r) {
        const int row = bm + wm2 * 128 + mi * 16 + quad * 4 + r;
        const float v = (acc[mi][nj][r] + bv) * sc;
        if (OUT_BF16)
          ((ushort*)Cout)[(size_t)row * N + col] = f2bf(v);
        else
          ((float*)Cout)[(size_t)row * N + col] = v;
      }
    }
}

// Out projection (R13-proven): BM=64, BN=128, BK=32, 512 blocks (2/CU).
// A=yb bf16 via glds; B=out_w f32 reg-loaded + cvt_pk + ds_write to the
// glds-identical address. __syncthreads() drains both counters.
__global__ __launch_bounds__(256) void gemm_out64f(const ushort* __restrict__ A,
                                                   const float* __restrict__ Bf,
                                                   const float* __restrict__ bias,
                                                   float* __restrict__ C,
                                                   int M, int N, int K) {
  __shared__ ushort As[64 * 32];
  __shared__ ushort Bs[128 * 32];
  const int t = threadIdx.x;
  const int wid = t >> 6, lane = t & 63;
  const int quad = lane >> 4, l16 = lane & 15;
  const int bm = blockIdx.y * 64, bn = blockIdx.x * 128;
  const int wn = wid * 32;

  f32x4 acc[4][2];
  const f32x4 z = {0.f, 0.f, 0.f, 0.f};
#pragma unroll
  for (int i = 0; i < 4; ++i) { acc[i][0] = z; acc[i][1] = z; }

  const ushort* ag = A + (size_t)(bm + (t >> 2)) * K + ((t & 3) * 8);
  const float* bgf = Bf + (size_t)(bn + (t >> 2)) * K + ((t & 3) * 8);
  ushort* asl = As + wid * 512;
  const int bw = wid * 512 + lane * 8;  // glds-identical Bs ushort index
  const size_t rowskipf = (size_t)64 * K;

  for (int k0 = 0; k0 < K; k0 += 32) {
    glds16(ag + k0, asl);
    {
      const float* p0 = bgf + k0;
      const float* p1 = bgf + k0 + rowskipf;
      float4 c0 = *(const float4*)p0, c1 = *(const float4*)(p0 + 4);
      float4 c2 = *(const float4*)p1, c3 = *(const float4*)(p1 + 4);
      *(uint4*)&Bs[bw] = pk8(c0, c1);
      *(uint4*)&Bs[2048 + bw] = pk8(c2, c3);
    }
    __syncthreads();
    bf16x8 af[4], bff[2];
#pragma unroll
    for (int i = 0; i < 4; ++i)
      af[i] = *(const bf16x8*)(As + (i * 16 + l16) * 32 + quad * 8);
#pragma unroll
    for (int j = 0; j < 2; ++j)
      bff[j] = *(const bf16x8*)(Bs + (wn + j * 16 + l16) * 32 + quad * 8);
#pragma unroll
    for (int i = 0; i < 4; ++i)
#pragma unroll
      for (int j = 0; j < 2; ++j)
        acc[i][j] = __builtin_amdgcn_mfma_f32_16x16x32_bf16(af[i], bff[j], acc[i][j], 0, 0, 0);
    __syncthreads();
  }

#pragma unroll
  for (int i = 0; i < 4; ++i)
#pragma unroll
    for (int j = 0; j < 2; ++j) {
      const int col = bn + wn + j * 16 + l16;
      const float bv = bias[col];
#pragma unroll
      for (int r = 0; r < 4; ++r) {
        const int row = bm + i * 16 + quad * 4 + r;
        C[(size_t)row * N + col] = acc[i][j][r] + bv;
      }
    }
}

// Per-(bh,chunk) KV sums via MFMA: mlocT[bh][c][e][f] = sum_s v[s][e]*k[s][f].
__global__ __launch_bounds__(256) void kv_local(const ushort* __restrict__ qkv,
                                                float* __restrict__ mlocT) {
  const int c = blockIdx.x, bh = blockIdx.y;
  const int b = bh >> 4, hd = bh & 15;
  const int t = threadIdx.x;
  const int wid = t >> 6, lane = t & 63;
  const int quad = lane >> 4, l16 = lane & 15;
  __shared__ ushort kT[64 * 136];  // [f:64][s:128] pad 8
  __shared__ ushort vT[64 * 136];  // [e:64][s:128] pad 8

  {
    const int x = t & 127;
    const int isv = t >> 7;
    const int rp = x >> 1;          // rows 2rp, 2rp+1
    const int half = (x & 1) * 32;  // j-range half..half+31
    const ushort* g0 = qkv + (size_t)(b * 2048 + c * 128 + 2 * rp) * 3072 +
                       1024 + isv * 1024 + hd * 64 + half;
    const ushort* g1 = g0 + 3072;
    ushort ta[32], tb[32];
#pragma unroll
    for (int q = 0; q < 4; ++q) {
      *(uint4*)(ta + q * 8) = *(const uint4*)(g0 + q * 8);
      *(uint4*)(tb + q * 8) = *(const uint4*)(g1 + q * 8);
    }
    ushort* dst = isv ? vT : kT;
#pragma unroll
    for (int j = 0; j < 32; ++j) {
      unsigned pk = (unsigned)ta[j] | ((unsigned)tb[j] << 16);
      *(unsigned*)(dst + (half + j) * 136 + 2 * rp) = pk;
    }
  }
  __syncthreads();

  const f32x4 z = {0.f, 0.f, 0.f, 0.f};
  f32x4 acc[4];
#pragma unroll
  for (int ct = 0; ct < 4; ++ct) acc[ct] = z;
#pragma unroll
  for (int kc = 0; kc < 4; ++kc) {
    bf16x8 afr = *(const bf16x8*)(vT + (wid * 16 + l16) * 136 + kc * 32 + quad * 8);
#pragma unroll
    for (int ct = 0; ct < 4; ++ct) {
      bf16x8 bfr = *(const bf16x8*)(kT + (ct * 16 + l16) * 136 + kc * 32 + quad * 8);
      acc[ct] = __builtin_amdgcn_mfma_f32_16x16x32_bf16(afr, bfr, acc[ct], 0, 0, 0);
    }
  }

  float* outp = mlocT + ((size_t)bh * 16 + c) * 4096;
#pragma unroll
  for (int ct = 0; ct < 4; ++ct)
#pragma unroll
    for (int r = 0; r < 4; ++r)
      outp[(wid * 16 + quad * 4 + r) * 64 + ct * 16 + l16] = acc[ct][r];
}

// Exclusive prefix over chunks, parallel over 4096 (e,f) entries per bh.
__global__ __launch_bounds__(256) void kv_prefix(const float* __restrict__ mlocT,
                                                 ushort* __restrict__ statesT) {
  const int slice = blockIdx.x, bh = blockIdx.y;
  const int eidx = slice * 256 + threadIdx.x;
  float run = 0.f;
  for (int c = 0; c < 16; ++c) {
    const size_t idx = ((size_t)bh * 16 + c) * 4096 + eidx;
    statesT[idx] = f2bf(run);
    run += mlocT[idx];
  }
}

// Per-(bh,chunk): P = tril(Q K^T) ; Y = P V + Q S_prefix (state from statesT).
__global__ __launch_bounds__(256) void attn_chunk(const ushort* __restrict__ qkv,
                                                  const ushort* __restrict__ statesT,
                                                  ushort* __restrict__ yb) {
  const int c = blockIdx.x, bh = blockIdx.y;
  const int b = bh >> 4, hd = bh & 15;
  const int l0 = c * 128;
  const int t = threadIdx.x;
  const int wid = t >> 6, lane = t & 63;
  const int quad = lane >> 4, l16 = lane & 15;

  __shared__ ushort P[16384];  // [row][16B chunks] XOR-swizzled by row&7
  __shared__ ushort U[16384];
  ushort* Qs = U;              // [row:128][64] chunk^(row&7)
  ushort* Ks = U + 8192;
  ushort* vT = U;              // phase2: [e:64][s:128] stride 136
  ushort* sT = U + 8704;       // phase2: [e:64][f:64]  stride 72

  {  // zero P
    uint4 zz; zz.x = zz.y = zz.z = zz.w = 0u;
    uint4* p4 = (uint4*)P;
#pragma unroll
    for (int i = 0; i < 8; ++i) p4[i * 256 + t] = zz;
  }
  {  // stage Q,K swizzled
    const int kcs = ((lane & 7) ^ (lane >> 3)) * 8;
    const ushort* qg = qkv + (size_t)(b * 2048 + l0 + (t >> 3)) * 3072 + hd * 64 + kcs;
    ushort* ql = Qs + wid * 512;
    ushort* kl = Ks + wid * 512;
#pragma unroll
    for (int h2 = 0; h2 < 4; ++h2) {
      glds16(qg + (size_t)h2 * 32 * 3072, ql + h2 * 2048);
      glds16(qg + (size_t)h2 * 32 * 3072 + 1024, kl + h2 * 2048);
    }
  }
  __syncthreads();

  bf16x8 qf[2][2];
#pragma unroll
  for (int i = 0; i < 2; ++i) {
    const int rt = i ? (7 - wid) : wid;
#pragma unroll
    for (int kc = 0; kc < 2; ++kc)
      qf[i][kc] = *(const bf16x8*)(Qs + (rt * 16 + l16) * 64 +
                                   (((kc * 4 + quad) ^ (l16 & 7)) * 8));
  }

  const f32x4 z4 = {0.f, 0.f, 0.f, 0.f};
  f32x4 pacc[2][8];
#pragma unroll
  for (int i = 0; i < 2; ++i)
#pragma unroll
    for (int j = 0; j < 8; ++j) pacc[i][j] = z4;

#pragma unroll
  for (int i = 0; i < 2; ++i) {
    const int rt = i ? (7 - wid) : wid;
#pragma unroll
    for (int tj = 0; tj < 8; ++tj) {
      if (tj <= rt) {
#pragma unroll
        for (int kc = 0; kc < 2; ++kc) {
          bf16x8 kfr = *(const bf16x8*)(Ks + (tj * 16 + l16) * 64 +
                                        (((kc * 4 + quad) ^ (l16 & 7)) * 8));
          pacc[i][tj] = __builtin_amdgcn_mfma_f32_16x16x32_bf16(qf[i][kc], kfr, pacc[i][tj], 0, 0, 0);
        }
      }
    }
  }
  __syncthreads();

#pragma unroll
  for (int i = 0; i < 2; ++i) {
    const int rt = i ? (7 - wid) : wid;
#pragma unroll
    for (int tj = 0; tj < 8; ++tj) {
      if (tj <= rt) {
#pragma unroll
        for (int r = 0; r < 4; ++r) {
          const int row = rt * 16 + quad * 4 + r;
          const int scol = tj * 16 + l16;
          const float v = (scol <= row) ? pacc[i][tj][r] : 0.f;
          P[row * 128 + (((scol >> 3) ^ (row & 7)) * 8) + (scol & 7)] = f2bf(v);
        }
      }
    }
  }
  {  // stage V transposed: vT[e][s] stride 136, s-pair-packed b32 writes
    const int p = t >> 2;              // s-pair: s = 2p, 2p+1
    const int eq = (t & 3) * 16;       // e-quarter
    const ushort* vg0 = qkv + (size_t)(b * 2048 + l0 + 2 * p) * 3072 + 2048 + hd * 64 + eq;
    const ushort* vg1 = vg0 + 3072;
    ushort ta[16], tb[16];
    *(uint4*)(ta + 0) = *(const uint4*)(vg0 + 0);
    *(uint4*)(ta + 8) = *(const uint4*)(vg0 + 8);
    *(uint4*)(tb + 0) = *(const uint4*)(vg1 + 0);
    *(uint4*)(tb + 8) = *(const uint4*)(vg1 + 8);
#pragma unroll
    for (int j = 0; j < 16; ++j) {
      unsigned pk = (unsigned)ta[j] | ((unsigned)tb[j] << 16);
      *(unsigned*)(vT + (eq + j) * 136 + 2 * p) = pk;
    }
  }
  {  // stage state: 2 coalesced uint4 per thread -> sT stride 72
    const ushort* sg = statesT + ((size_t)bh * 16 + c) * 4096;
#pragma unroll
    for (int h = 0; h < 2; ++h) {
      const int cc = h * 256 + t;
      uint4 d = *(const uint4*)(sg + cc * 8);
      *(uint4*)(sT + (cc >> 3) * 72 + (cc & 7) * 8) = d;
    }
  }
  __syncthreads();

  f32x4 yacc[2][4];
#pragma unroll
  for (int i = 0; i < 2; ++i)
#pragma unroll
    for (int j = 0; j < 4; ++j) yacc[i][j] = z4;

#pragma unroll
  for (int i = 0; i < 2; ++i) {
    const int rt = i ? (7 - wid) : wid;
    const int kcmax = rt >> 1;
#pragma unroll
    for (int kc = 0; kc < 4; ++kc) {
      if (kc <= kcmax) {
        const int prow = rt * 16 + l16;
        bf16x8 pf;
        *(uint4*)&pf = *(const uint4*)(P + prow * 128 + (((kc * 4 + quad) ^ (prow & 7)) * 8));
#pragma unroll
        for (int ct = 0; ct < 4; ++ct) {
          bf16x8 vf = *(const bf16x8*)(vT + (ct * 16 + l16) * 136 + kc * 32 + quad * 8);
          yacc[i][ct] = __builtin_amdgcn_mfma_f32_16x16x32_bf16(pf, vf, yacc[i][ct], 0, 0, 0);
        }
      }
    }
#pragma unroll
    for (int kc = 0; kc < 2; ++kc) {
#pragma unroll
      for (int ct = 0; ct < 4; ++ct) {
        bf16x8 sf = *(const bf16x8*)(sT + (ct * 16 + l16) * 72 + kc * 32 + quad * 8);
        yacc[i][ct] = __builtin_amdgcn_mfma_f32_16x16x32_bf16(qf[i][kc], sf, yacc[i][ct], 0, 0, 0);
      }
    }
  }

#pragma unroll
  for (int i = 0; i < 2; ++i) {
    const int rt = i ? (7 - wid) : wid;
#pragma unroll
    for (int ct = 0; ct < 4; ++ct) {
#pragma unroll
      for (int r = 0; r < 4; ++r) {
        const int row = rt * 16 + quad * 4 + r;
        const int e = ct * 16 + l16;
        yb[(size_t)(b * 2048 + l0 + row) * 1024 + hd * 64 + e] = f2bf(yacc[i][ct][r]);
      }
    }
  }
}

extern "C" void kernel_launch(void* const* d_in, const int* in_sizes, int n_in,
                              void* d_out, int out_size, void* d_ws, size_t ws_size,
                              hipStream_t stream) {
  const float* x  = (const float*)d_in[0];
  const float* Ww = (const float*)d_in[1];
  const float* Wb = (const float*)d_in[2];
  const float* Ow = (const float*)d_in[3];
  const float* Ob = (const float*)d_in[4];
  float* out = (float*)d_out;

  char* ws = (char*)d_ws;
  ushort* xb      = (ushort*)(ws);
  ushort* wqkvb   = (ushort*)(ws + (size_t)8  * 1024 * 1024);
  ushort* qkvb    = (ushort*)(ws + (size_t)16 * 1024 * 1024);
  float*  mlocT   = (float*) (ws + (size_t)40 * 1024 * 1024);
  ushort* statesT = (ushort*)(ws + (size_t)48 * 1024 * 1024);
  ushort* yb      = (ushort*)(ws + (size_t)52 * 1024 * 1024);

  cvt_all2<<<7168, 256, 0, stream>>>(x, Ww, xb, wqkvb);
  // 256^2 tiles: grid = (3072/256)*(4096/256) = 192 blocks (1D, XCD-swizzled).
  gemm_bt8<true, true><<<dim3(192), 512, 0, stream>>>(xb, wqkvb, Wb, (void*)qkvb, 4096, 3072, 1024);
  kv_local<<<dim3(16, 32), 256, 0, stream>>>(qkvb, mlocT);
  kv_prefix<<<dim3(16, 32), 256, 0, stream>>>(mlocT, statesT);
  attn_chunk<<<dim3(16, 32), 256, 0, stream>>>(qkvb, statesT, yb);
  gemm_out64f<<<dim3(8, 64), 256, 0, stream>>>(yb, Ow, Ob, out, 4096, 1024, 1024);
}

// Round 11
// 160.237 us; speedup vs baseline: 1.7809x; 1.0362x over previous
//
#include <hip/hip_runtime.h>

// LinearAttention: B=2, L=2048, D=1024, H=16, d=64.
// R16 = R11-exact resubmission (session best, 159.66us, twice-measured).
// cvt_all ; gemm_bt8 (R1-proven 256^2 tile-dbuf) ; kv_local (packed b32
// transpose) ; kv_prefix ; attn_chunk (causal-balanced rt={wid,7-wid},
// packed V transpose) ; gemm_out64.
// Session landscape (all measured): QKV schedules 40/43/50/72us -> R1's 40
// is the optimum; attn causal balance null (not compute-bound); prefix
// fusion +7us; cooperative grid.sync fusion +125us; inline-cvt staging
// loses wherever the staging chain is critical-path (QKV +21us, out64
// +5us -- m151: reg-staging < global_load_lds). R11 config = confirmed
// local optimum; resubmitted verbatim per R15 pre-commitment.

#define DEV __device__ __forceinline__

typedef __attribute__((ext_vector_type(8))) short bf16x8;
typedef __attribute__((ext_vector_type(4))) float f32x4;

DEV ushort f2bf(float f) {
  union { float f; unsigned u; } v; v.f = f;
  unsigned r = v.u + 0x7fffu + ((v.u >> 16) & 1u);
  return (ushort)(r >> 16);
}
DEV float bf2f(unsigned b) {
  union { unsigned u; float f; } v; v.u = (b & 0xffffu) << 16;
  return v.f;
}
DEV void glds16(const ushort* g, ushort* l) {
  __builtin_amdgcn_global_load_lds(
      (const __attribute__((address_space(1))) unsigned int*)g,
      (__attribute__((address_space(3))) unsigned int*)l, 16, 0, 0);
}

__global__ __launch_bounds__(256) void cvt_all(const float* __restrict__ x,
                                               const float* __restrict__ Ww,
                                               const float* __restrict__ Ow,
                                               ushort* __restrict__ xb,
                                               ushort* __restrict__ wqkvb,
                                               ushort* __restrict__ outwb) {
  int i = blockIdx.x * 256 + threadIdx.x;
  const float* src; ushort* dst; int off;
  if (i < 1048576)      { src = x;  dst = xb;    off = i; }
  else if (i < 1835008) { src = Ww; dst = wqkvb; off = i - 1048576; }
  else                  { src = Ow; dst = outwb; off = i - 1835008; }
  float4 v = ((const float4*)src)[off];
  ushort4 o;
  o.x = f2bf(v.x); o.y = f2bf(v.y); o.z = f2bf(v.z); o.w = f2bf(v.w);
  ((ushort4*)dst)[off] = o;
}

// ---------------------------------------------------------------------------
// QKV GEMM (R1-proven): 256x256 tiles, BK=64 dbuf, 8 waves (2M x 4N),
// 4 phases/tile with raw barriers, vmcnt(0) twice per 8 phases, T2 swizzle
// (pre-swizzled global source + XOR ds_read), T1 XCD swizzle, T5 setprio.
// ---------------------------------------------------------------------------
template <bool OUT_BF16, bool KSCALE>
__global__ __launch_bounds__(512, 2) void gemm_bt8(const ushort* __restrict__ A,
                                                   const ushort* __restrict__ Bw,
                                                   const float* __restrict__ bias,
                                                   void* __restrict__ Cout,
                                                   int M, int N, int K) {
  __shared__ __align__(16) ushort As[2][16384];
  __shared__ __align__(16) ushort Bs[2][16384];
  const int t = threadIdx.x;
  const int lane = t & 63, wid = t >> 6;
  const int quad = lane >> 4, l16 = lane & 15;
  const int wm2 = wid >> 2, wn4 = wid & 3;

  const int nwg = gridDim.x;
  const int bid = blockIdx.x;
  const int wg = (bid & 7) * (nwg >> 3) + (bid >> 3);
  const int nbx = N >> 8;
  const int bx = wg % nbx, by = wg / nbx;
  const int bm = by << 8, bn = bx << 8;

  const int srow = t >> 3;
  const int scol = ((t & 7) ^ (srow & 7)) << 3;
  const ushort* ag = A + (size_t)(bm + srow) * K + scol;
  const ushort* bg = Bw + (size_t)(bn + srow) * K + scol;
  const int NT = K >> 6;

  f32x4 acc[8][4];
  const f32x4 z = {0.f, 0.f, 0.f, 0.f};
#pragma unroll
  for (int i = 0; i < 8; ++i)
#pragma unroll
    for (int j = 0; j < 4; ++j) acc[i][j] = z;

  const int aRow = wm2 * 128 + l16;
  const int bRow = wn4 * 64 + l16;
  const int cxor = l16 & 7;

#define SG_A(bufi, kt, h, j) \
  glds16(ag + (size_t)((h)*128 + (j)*64) * K + ((kt) << 6), \
         &As[bufi][(h)*8192 + (j)*4096 + wid * 512])
#define SG_B(bufi, kt, h, j) \
  glds16(bg + (size_t)((h)*128 + (j)*64) * K + ((kt) << 6), \
         &Bs[bufi][(h)*8192 + (j)*4096 + wid * 512])
#define RD_A(bufi, mi, kc) \
  (*(const bf16x8*)&As[bufi][(aRow + (mi)*16) * 64 + ((((kc)*4 + quad) ^ cxor) << 3)])
#define RD_B(bufi, nj, kc) \
  (*(const bf16x8*)&Bs[bufi][(bRow + (nj)*16) * 64 + ((((kc)*4 + quad) ^ cxor) << 3)])

  SG_A(0, 0, 0, 0); SG_A(0, 0, 0, 1); SG_A(0, 0, 1, 0); SG_A(0, 0, 1, 1);
  SG_B(0, 0, 0, 0); SG_B(0, 0, 0, 1); SG_B(0, 0, 1, 0); SG_B(0, 0, 1, 1);
  asm volatile("s_waitcnt vmcnt(0)" ::: "memory");
  __builtin_amdgcn_s_barrier();

  bf16x8 bf[4][2], af[2][2];

#define LOAD_AF(rb, mi0) \
  af[0][0] = RD_A(rb, (mi0), 0); af[0][1] = RD_A(rb, (mi0), 1); \
  af[1][0] = RD_A(rb, (mi0) + 1, 0); af[1][1] = RD_A(rb, (mi0) + 1, 1);

#define MFMA16(mi0) \
  __builtin_amdgcn_s_setprio(1); \
  _Pragma("unroll") \
  for (int nj = 0; nj < 4; ++nj) { \
    acc[(mi0)][nj] = __builtin_amdgcn_mfma_f32_16x16x32_bf16(af[0][0], bf[nj][0], acc[(mi0)][nj], 0, 0, 0); \
    acc[(mi0)][nj] = __builtin_amdgcn_mfma_f32_16x16x32_bf16(af[0][1], bf[nj][1], acc[(mi0)][nj], 0, 0, 0); \
    acc[(mi0) + 1][nj] = __builtin_amdgcn_mfma_f32_16x16x32_bf16(af[1][0], bf[nj][0], acc[(mi0) + 1][nj], 0, 0, 0); \
    acc[(mi0) + 1][nj] = __builtin_amdgcn_mfma_f32_16x16x32_bf16(af[1][1], bf[nj][1], acc[(mi0) + 1][nj], 0, 0, 0); \
  } \
  __builtin_amdgcn_s_setprio(0);

#define HALFSTEP(rb, sb, stTile, doSt) do { \
    if (doSt) { SG_A(sb, stTile, 0, 0); SG_A(sb, stTile, 0, 1); \
                SG_A(sb, stTile, 1, 0); SG_A(sb, stTile, 1, 1); } \
    _Pragma("unroll") \
    for (int nj = 0; nj < 4; ++nj) { bf[nj][0] = RD_B(rb, nj, 0); bf[nj][1] = RD_B(rb, nj, 1); } \
    LOAD_AF(rb, 0); \
    __builtin_amdgcn_s_barrier(); \
    MFMA16(0); \
    __builtin_amdgcn_s_barrier(); \
    if (doSt) { SG_B(sb, stTile, 0, 0); SG_B(sb, stTile, 0, 1); } \
    LOAD_AF(rb, 2); \
    __builtin_amdgcn_s_barrier(); \
    MFMA16(2); \
    __builtin_amdgcn_s_barrier(); \
    if (doSt) { SG_B(sb, stTile, 1, 0); SG_B(sb, stTile, 1, 1); } \
    LOAD_AF(rb, 4); \
    __builtin_amdgcn_s_barrier(); \
    MFMA16(4); \
    __builtin_amdgcn_s_barrier(); \
    LOAD_AF(rb, 6); \
    __builtin_amdgcn_s_barrier(); \
    MFMA16(6); \
    asm volatile("s_waitcnt vmcnt(0)" ::: "memory"); \
    __builtin_amdgcn_s_barrier(); \
  } while (0)

  const int half = NT >> 1;
  for (int i = 0; i < half; ++i) {
    HALFSTEP(0, 1, 2 * i + 1, true);
    HALFSTEP(1, 0, 2 * i + 2, (i < half - 1));
  }

#undef HALFSTEP
#undef MFMA16
#undef LOAD_AF
#undef RD_A
#undef RD_B
#undef SG_A
#undef SG_B

#pragma unroll
  for (int mi = 0; mi < 8; ++mi)
#pragma unroll
    for (int nj = 0; nj < 4; ++nj) {
      const int col = bn + wn4 * 64 + nj * 16 + l16;
      const float bv = bias[col];
      float sc = 1.f;
      if (KSCALE) sc = ((col >> 10) == 1) ? 0.125f : 1.f;
#pragma unroll
      for (int r = 0; r < 4; ++r) {
        const int row = bm + wm2 * 128 + mi * 16 + quad * 4 + r;
        const float v = (acc[mi][nj][r] + bv) * sc;
        if (OUT_BF16)
          ((ushort*)Cout)[(size_t)row * N + col] = f2bf(v);
        else
          ((float*)Cout)[(size_t)row * N + col] = v;
      }
    }
}

// Out projection: BM=64, BN=128, BK=32 -> 512 blocks (2/CU), identity staging.
__global__ __launch_bounds__(256) void gemm_out64(const ushort* __restrict__ A,
                                                  const ushort* __restrict__ Bw,
                                                  const float* __restrict__ bias,
                                                  float* __restrict__ C,
                                                  int M, int N, int K) {
  __shared__ ushort As[64 * 32];
  __shared__ ushort Bs[128 * 32];
  const int t = threadIdx.x;
  const int wid = t >> 6, lane = t & 63;
  const int quad = lane >> 4, l16 = lane & 15;
  const int bm = blockIdx.y * 64, bn = blockIdx.x * 128;
  const int wn = wid * 32;

  f32x4 acc[4][2];
  const f32x4 z = {0.f, 0.f, 0.f, 0.f};
#pragma unroll
  for (int i = 0; i < 4; ++i) { acc[i][0] = z; acc[i][1] = z; }

  const ushort* ag = A + (size_t)(bm + (t >> 2)) * K + ((t & 3) * 8);
  const ushort* bg = Bw + (size_t)(bn + (t >> 2)) * K + ((t & 3) * 8);
  ushort* asl = As + wid * 512;
  ushort* bsl = Bs + wid * 512;
  const size_t rowskip = (size_t)64 * K;

  for (int k0 = 0; k0 < K; k0 += 32) {
    glds16(ag + k0, asl);
    glds16(bg + k0, bsl);
    glds16(bg + k0 + rowskip, bsl + 2048);
    __syncthreads();
    bf16x8 af[4], bf[2];
#pragma unroll
    for (int i = 0; i < 4; ++i)
      af[i] = *(const bf16x8*)(As + (i * 16 + l16) * 32 + quad * 8);
#pragma unroll
    for (int j = 0; j < 2; ++j)
      bf[j] = *(const bf16x8*)(Bs + (wn + j * 16 + l16) * 32 + quad * 8);
#pragma unroll
    for (int i = 0; i < 4; ++i)
#pragma unroll
      for (int j = 0; j < 2; ++j)
        acc[i][j] = __builtin_amdgcn_mfma_f32_16x16x32_bf16(af[i], bf[j], acc[i][j], 0, 0, 0);
    __syncthreads();
  }

#pragma unroll
  for (int i = 0; i < 4; ++i)
#pragma unroll
    for (int j = 0; j < 2; ++j) {
      const int col = bn + wn + j * 16 + l16;
      const float bv = bias[col];
#pragma unroll
      for (int r = 0; r < 4; ++r) {
        const int row = bm + i * 16 + quad * 4 + r;
        C[(size_t)row * N + col] = acc[i][j][r] + bv;
      }
    }
}

// Per-(bh,chunk) KV sums via MFMA: mlocT[bh][c][e][f] = sum_s v[s][e]*k[s][f].
// Transpose staging packs row-pairs into ds_write_b32 (32 writes vs 64).
__global__ __launch_bounds__(256) void kv_local(const ushort* __restrict__ qkv,
                                                float* __restrict__ mlocT) {
  const int c = blockIdx.x, bh = blockIdx.y;
  const int b = bh >> 4, hd = bh & 15;
  const int t = threadIdx.x;
  const int wid = t >> 6, lane = t & 63;
  const int quad = lane >> 4, l16 = lane & 15;
  __shared__ ushort kT[64 * 136];  // [f:64][s:128] pad 8
  __shared__ ushort vT[64 * 136];  // [e:64][s:128] pad 8

  {
    const int x = t & 127;
    const int isv = t >> 7;
    const int rp = x >> 1;          // rows 2rp, 2rp+1
    const int half = (x & 1) * 32;  // j-range half..half+31
    const ushort* g0 = qkv + (size_t)(b * 2048 + c * 128 + 2 * rp) * 3072 +
                       1024 + isv * 1024 + hd * 64 + half;
    const ushort* g1 = g0 + 3072;
    ushort ta[32], tb[32];
#pragma unroll
    for (int q = 0; q < 4; ++q) {
      *(uint4*)(ta + q * 8) = *(const uint4*)(g0 + q * 8);
      *(uint4*)(tb + q * 8) = *(const uint4*)(g1 + q * 8);
    }
    ushort* dst = isv ? vT : kT;
#pragma unroll
    for (int j = 0; j < 32; ++j) {
      unsigned pk = (unsigned)ta[j] | ((unsigned)tb[j] << 16);
      *(unsigned*)(dst + (half + j) * 136 + 2 * rp) = pk;
    }
  }
  __syncthreads();

  const f32x4 z = {0.f, 0.f, 0.f, 0.f};
  f32x4 acc[4];
#pragma unroll
  for (int ct = 0; ct < 4; ++ct) acc[ct] = z;
#pragma unroll
  for (int kc = 0; kc < 4; ++kc) {
    bf16x8 afr = *(const bf16x8*)(vT + (wid * 16 + l16) * 136 + kc * 32 + quad * 8);
#pragma unroll
    for (int ct = 0; ct < 4; ++ct) {
      bf16x8 bfr = *(const bf16x8*)(kT + (ct * 16 + l16) * 136 + kc * 32 + quad * 8);
      acc[ct] = __builtin_amdgcn_mfma_f32_16x16x32_bf16(afr, bfr, acc[ct], 0, 0, 0);
    }
  }

  float* outp = mlocT + ((size_t)bh * 16 + c) * 4096;
#pragma unroll
  for (int ct = 0; ct < 4; ++ct)
#pragma unroll
    for (int r = 0; r < 4; ++r)
      outp[(wid * 16 + quad * 4 + r) * 64 + ct * 16 + l16] = acc[ct][r];
}

// Exclusive prefix over chunks, parallel over 4096 (e,f) entries per bh.
__global__ __launch_bounds__(256) void kv_prefix(const float* __restrict__ mlocT,
                                                 ushort* __restrict__ statesT) {
  const int slice = blockIdx.x, bh = blockIdx.y;
  const int eidx = slice * 256 + threadIdx.x;
  float run = 0.f;
  for (int c = 0; c < 16; ++c) {
    const size_t idx = ((size_t)bh * 16 + c) * 4096 + eidx;
    statesT[idx] = f2bf(run);
    run += mlocT[idx];
  }
}

// Per-(bh,chunk): P = tril(Q K^T) ; Y = P V + Q S_prefix (state from statesT).
// Causal load-balance: wave wid owns row-tiles {wid, 7-wid}; V transpose
// packed b32.
__global__ __launch_bounds__(256) void attn_chunk(const ushort* __restrict__ qkv,
                                                  const ushort* __restrict__ statesT,
                                                  ushort* __restrict__ yb) {
  const int c = blockIdx.x, bh = blockIdx.y;
  const int b = bh >> 4, hd = bh & 15;
  const int l0 = c * 128;
  const int t = threadIdx.x;
  const int wid = t >> 6, lane = t & 63;
  const int quad = lane >> 4, l16 = lane & 15;

  __shared__ ushort P[16384];  // [row][16B chunks] XOR-swizzled by row&7
  __shared__ ushort U[16384];
  ushort* Qs = U;              // [row:128][64] chunk^(row&7)
  ushort* Ks = U + 8192;
  ushort* vT = U;              // phase2: [e:64][s:128] stride 136
  ushort* sT = U + 8704;       // phase2: [e:64][f:64]  stride 72

  {  // zero P
    uint4 zz; zz.x = zz.y = zz.z = zz.w = 0u;
    uint4* p4 = (uint4*)P;
#pragma unroll
    for (int i = 0; i < 8; ++i) p4[i * 256 + t] = zz;
  }
  {  // stage Q,K swizzled
    const int kcs = ((lane & 7) ^ (lane >> 3)) * 8;
    const ushort* qg = qkv + (size_t)(b * 2048 + l0 + (t >> 3)) * 3072 + hd * 64 + kcs;
    ushort* ql = Qs + wid * 512;
    ushort* kl = Ks + wid * 512;
#pragma unroll
    for (int h2 = 0; h2 < 4; ++h2) {
      glds16(qg + (size_t)h2 * 32 * 3072, ql + h2 * 2048);
      glds16(qg + (size_t)h2 * 32 * 3072 + 1024, kl + h2 * 2048);
    }
  }
  __syncthreads();

  bf16x8 qf[2][2];
#pragma unroll
  for (int i = 0; i < 2; ++i) {
    const int rt = i ? (7 - wid) : wid;
#pragma unroll
    for (int kc = 0; kc < 2; ++kc)
      qf[i][kc] = *(const bf16x8*)(Qs + (rt * 16 + l16) * 64 +
                                   (((kc * 4 + quad) ^ (l16 & 7)) * 8));
  }

  const f32x4 z4 = {0.f, 0.f, 0.f, 0.f};
  f32x4 pacc[2][8];
#pragma unroll
  for (int i = 0; i < 2; ++i)
#pragma unroll
    for (int j = 0; j < 8; ++j) pacc[i][j] = z4;

#pragma unroll
  for (int i = 0; i < 2; ++i) {
    const int rt = i ? (7 - wid) : wid;
#pragma unroll
    for (int tj = 0; tj < 8; ++tj) {
      if (tj <= rt) {
#pragma unroll
        for (int kc = 0; kc < 2; ++kc) {
          bf16x8 kfr = *(const bf16x8*)(Ks + (tj * 16 + l16) * 64 +
                                        (((kc * 4 + quad) ^ (l16 & 7)) * 8));
          pacc[i][tj] = __builtin_amdgcn_mfma_f32_16x16x32_bf16(qf[i][kc], kfr, pacc[i][tj], 0, 0, 0);
        }
      }
    }
  }
  __syncthreads();

#pragma unroll
  for (int i = 0; i < 2; ++i) {
    const int rt = i ? (7 - wid) : wid;
#pragma unroll
    for (int tj = 0; tj < 8; ++tj) {
      if (tj <= rt) {
#pragma unroll
        for (int r = 0; r < 4; ++r) {
          const int row = rt * 16 + quad * 4 + r;
          const int scol = tj * 16 + l16;
          const float v = (scol <= row) ? pacc[i][tj][r] : 0.f;
          P[row * 128 + (((scol >> 3) ^ (row & 7)) * 8) + (scol & 7)] = f2bf(v);
        }
      }
    }
  }
  {  // stage V transposed: vT[e][s] stride 136, s-pair-packed b32 writes
    const int p = t >> 2;              // s-pair: s = 2p, 2p+1
    const int eq = (t & 3) * 16;       // e-quarter
    const ushort* vg0 = qkv + (size_t)(b * 2048 + l0 + 2 * p) * 3072 + 2048 + hd * 64 + eq;
    const ushort* vg1 = vg0 + 3072;
    ushort ta[16], tb[16];
    *(uint4*)(ta + 0) = *(const uint4*)(vg0 + 0);
    *(uint4*)(ta + 8) = *(const uint4*)(vg0 + 8);
    *(uint4*)(tb + 0) = *(const uint4*)(vg1 + 0);
    *(uint4*)(tb + 8) = *(const uint4*)(vg1 + 8);
#pragma unroll
    for (int j = 0; j < 16; ++j) {
      unsigned pk = (unsigned)ta[j] | ((unsigned)tb[j] << 16);
      *(unsigned*)(vT + (eq + j) * 136 + 2 * p) = pk;
    }
  }
  {  // stage state: 2 coalesced uint4 per thread -> sT stride 72
    const ushort* sg = statesT + ((size_t)bh * 16 + c) * 4096;
#pragma unroll
    for (int h = 0; h < 2; ++h) {
      const int cc = h * 256 + t;
      uint4 d = *(const uint4*)(sg + cc * 8);
      *(uint4*)(sT + (cc >> 3) * 72 + (cc & 7) * 8) = d;
    }
  }
  __syncthreads();

  f32x4 yacc[2][4];
#pragma unroll
  for (int i = 0; i < 2; ++i)
#pragma unroll
    for (int j = 0; j < 4; ++j) yacc[i][j] = z4;

#pragma unroll
  for (int i = 0; i < 2; ++i) {
    const int rt = i ? (7 - wid) : wid;
    const int kcmax = rt >> 1;
#pragma unroll
    for (int kc = 0; kc < 4; ++kc) {
      if (kc <= kcmax) {
        const int prow = rt * 16 + l16;
        bf16x8 pf;
        *(uint4*)&pf = *(const uint4*)(P + prow * 128 + (((kc * 4 + quad) ^ (prow & 7)) * 8));
#pragma unroll
        for (int ct = 0; ct < 4; ++ct) {
          bf16x8 vf = *(const bf16x8*)(vT + (ct * 16 + l16) * 136 + kc * 32 + quad * 8);
          yacc[i][ct] = __builtin_amdgcn_mfma_f32_16x16x32_bf16(pf, vf, yacc[i][ct], 0, 0, 0);
        }
      }
    }
#pragma unroll
    for (int kc = 0; kc < 2; ++kc) {
#pragma unroll
      for (int ct = 0; ct < 4; ++ct) {
        bf16x8 sf = *(const bf16x8*)(sT + (ct * 16 + l16) * 72 + kc * 32 + quad * 8);
        yacc[i][ct] = __builtin_amdgcn_mfma_f32_16x16x32_bf16(qf[i][kc], sf, yacc[i][ct], 0, 0, 0);
      }
    }
  }

#pragma unroll
  for (int i = 0; i < 2; ++i) {
    const int rt = i ? (7 - wid) : wid;
#pragma unroll
    for (int ct = 0; ct < 4; ++ct) {
#pragma unroll
      for (int r = 0; r < 4; ++r) {
        const int row = rt * 16 + quad * 4 + r;
        const int e = ct * 16 + l16;
        yb[(size_t)(b * 2048 + l0 + row) * 1024 + hd * 64 + e] = f2bf(yacc[i][ct][r]);
      }
    }
  }
}

extern "C" void kernel_launch(void* const* d_in, const int* in_sizes, int n_in,
                              void* d_out, int out_size, void* d_ws, size_t ws_size,
                              hipStream_t stream) {
  const float* x  = (const float*)d_in[0];
  const float* Ww = (const float*)d_in[1];
  const float* Wb = (const float*)d_in[2];
  const float* Ow = (const float*)d_in[3];
  const float* Ob = (const float*)d_in[4];
  float* out = (float*)d_out;

  char* ws = (char*)d_ws;
  ushort* xb      = (ushort*)(ws);
  ushort* wqkvb   = (ushort*)(ws + (size_t)8  * 1024 * 1024);
  ushort* outwb   = (ushort*)(ws + (size_t)14 * 1024 * 1024);
  ushort* qkvb    = (ushort*)(ws + (size_t)16 * 1024 * 1024);
  float*  mlocT   = (float*) (ws + (size_t)40 * 1024 * 1024);
  ushort* statesT = (ushort*)(ws + (size_t)48 * 1024 * 1024);
  ushort* yb      = (ushort*)(ws + (size_t)52 * 1024 * 1024);

  cvt_all<<<8192, 256, 0, stream>>>(x, Ww, Ow, xb, wqkvb, outwb);
  // 256^2 tiles: grid = (3072/256)*(4096/256) = 192 blocks (1D, XCD-swizzled).
  gemm_bt8<true, true><<<dim3(192), 512, 0, stream>>>(xb, wqkvb, Wb, (void*)qkvb, 4096, 3072, 1024);
  kv_local<<<dim3(16, 32), 256, 0, stream>>>(qkvb, mlocT);
  kv_prefix<<<dim3(16, 32), 256, 0, stream>>>(mlocT, statesT);
  attn_chunk<<<dim3(16, 32), 256, 0, stream>>>(qkvb, statesT, yb);
  gemm_out64<<<dim3(8, 64), 256, 0, stream>>>(yb, outwb, Ob, out, 4096, 1024, 1024);
}